// Round 3
// baseline (470.167 us; speedup 1.0000x reference)
//
#include <hip/hip_runtime.h>

#define B_ 16
#define K_ 20
#define H_ 256
#define W_ 256
#define HW_ (H_*W_)
#define BK_ (B_*K_)
#define S_ 16        // strip rows per wave in fused
#define NSTRIP_ 16   // H_/S_

__device__ __forceinline__ float4 ld4(const float* p) { return *(const float4*)p; }
__device__ __forceinline__ float4 zero4() { return make_float4(0.f, 0.f, 0.f, 0.f); }

// exp(-(j-4)^2/50), j=0..8 (separable 2D gaussian: exp(-(di^2+dj^2)/50))
#define G0_ 0.72614903707f
#define G1_ 0.83527021141f
#define G2_ 0.92311634639f
#define G3_ 0.98019867331f

__global__ __launch_bounds__(256) void zero_ws_k(float* ws, int n) {
    int i = blockIdx.x * 256 + threadIdx.x;
    if (i < n) ws[i] = 0.f;
}

// Per-(b,k): sum(labels), sum(labels*inputs_c). One block = one (b,k,64-row chunk).
// XCD swizzle: blocks sharing (b,chunk) share blockIdx%8 -> same XCD L2 for inputs.
__global__ __launch_bounds__(256) void stats_k(const float* __restrict__ labels,
                                               const float* __restrict__ inputs,
                                               float* __restrict__ sums) {
    int idx = blockIdx.x;
    int low = idx & 7; int t1 = idx >> 3;
    int k = t1 % K_; int bch = t1 / K_;      // bch in 0..7
    int bc = bch * 8 + low;                  // bc = chunk + 4*b, in 0..63
    int chunk = bc & 3, b = bc >> 2;

    int tid = threadIdx.x;
    int rowi = tid >> 6;                     // 4 rows in flight
    int colo = (tid & 63) * 4;

    const float* lrow = labels + ((size_t)(b * K_ + k)) * HW_;
    const float* ip   = inputs + (size_t)b * 3 * HW_;

    float sl = 0.f, s0 = 0.f, s1 = 0.f, s2 = 0.f;
    int r0 = chunk * 64 + rowi;
#pragma unroll 4
    for (int it = 0; it < 16; ++it) {
        int off = (r0 + it * 4) * W_ + colo;
        float4 l  = ld4(lrow + off);
        float4 a  = ld4(ip + off);
        float4 bb = ld4(ip + HW_ + off);
        float4 cc = ld4(ip + 2 * HW_ + off);
        sl += (l.x + l.y) + (l.z + l.w);
        s0 += l.x * a.x  + l.y * a.y  + l.z * a.z  + l.w * a.w;
        s1 += l.x * bb.x + l.y * bb.y + l.z * bb.z + l.w * bb.w;
        s2 += l.x * cc.x + l.y * cc.y + l.z * cc.z + l.w * cc.w;
    }
#pragma unroll
    for (int o = 32; o > 0; o >>= 1) {
        sl += __shfl_xor(sl, o); s0 += __shfl_xor(s0, o);
        s1 += __shfl_xor(s1, o); s2 += __shfl_xor(s2, o);
    }
    __shared__ float rb[4][4];
    int wv = tid >> 6, lane = tid & 63;
    if (lane == 0) { rb[0][wv] = sl; rb[1][wv] = s0; rb[2][wv] = s1; rb[3][wv] = s2; }
    __syncthreads();
    if (tid == 0) {
        int bk = b * K_ + k;
        atomicAdd(&sums[bk],          rb[0][0] + rb[0][1] + rb[0][2] + rb[0][3]);
        atomicAdd(&sums[BK_ + bk],    rb[1][0] + rb[1][1] + rb[1][2] + rb[1][3]);
        atomicAdd(&sums[2*BK_ + bk],  rb[2][0] + rb[2][1] + rb[2][2] + rb[2][3]);
        atomicAdd(&sums[3*BK_ + bk],  rb[3][0] + rb[3][1] + rb[3][2] + rb[3][3]);
    }
}

__device__ __forceinline__ float4 hblur9(float4 vL, float4 v, float4 vR) {
    const float G[9] = {G0_, G1_, G2_, G3_, 1.0f, G3_, G2_, G1_, G0_};
    float w[12] = {vL.x, vL.y, vL.z, vL.w, v.x, v.y, v.z, v.w, vR.x, vR.y, vR.z, vR.w};
    float4 o = zero4();
#pragma unroll
    for (int j = 0; j < 9; ++j) {
        o.x += G[j] * w[j];     o.y += G[j] * w[j + 1];
        o.z += G[j] * w[j + 2]; o.w += G[j] * w[j + 3];
    }
    return o;
}

// Adjoint formulation: num = sum blur(l)*l*w, den = sum blur(l)*w  (G symmetric,
// zero-padded conv => sum a*(G*c) == sum (G*a)*c). Only LABELS gets blurred:
// single 9-deep float4 ring (36 VGPRs). One wave = one (b,k,16-row strip); lane
// holds 4 cols; wave = full 256-col row; horizontal blur via shuffles, no LDS.
__global__ __launch_bounds__(256, 4) void fused_k(const float* __restrict__ labels,
                                                  const float* __restrict__ inputs,
                                                  const float* __restrict__ sums,
                                                  float* __restrict__ numden) {
    const float G[9] = {G0_, G1_, G2_, G3_, 1.0f, G3_, G2_, G1_, G0_};
    int idx = blockIdx.x;
    int low = idx & 7; int t1 = idx >> 3;
    int kq = t1 % 5; int sbh = t1 / 5;
    int sb = sbh * 8 + low;          // sb = strip + 16*b; same (strip,b) -> same XCD
    int strip = sb & 15, b = sb >> 4;
    int tid = threadIdx.x;
    int lane = tid & 63, wv = tid >> 6;
    int k = kq * 4 + wv;             // 4 waves share input rows (L1 reuse)
    int bk = b * K_ + k;

    float dn  = sums[bk] + 1e-5f * (float)HW_;
    float inv = 1.f / dn;
    float cm0 = sums[BK_ + bk] * inv;
    float cm1 = sums[2 * BK_ + bk] * inv;
    float cm2 = sums[3 * BK_ + bk] * inv;
    float m2  = cm0 * cm0 + cm1 * cm1 + cm2 * cm2;

    const float* lrow = labels + (size_t)bk * HW_;
    const float* i0p = inputs + (size_t)b * 3 * HW_;
    const float* i1p = i0p + HW_;
    const float* i2p = i0p + 2 * HW_;
    const int colo = lane * 4;
    const int r0 = strip * S_;

    float4 hlr[9];   // horizontally-blurred labels ring

    auto loadrow = [&](int t, float4& ohl) {
        if ((unsigned)t < (unsigned)H_) {
            float4 l = ld4(lrow + t * W_ + colo);
            float4 ll, rr2;
            ll.x  = __shfl_up(l.x, 1);  ll.y  = __shfl_up(l.y, 1);
            ll.z  = __shfl_up(l.z, 1);  ll.w  = __shfl_up(l.w, 1);
            rr2.x = __shfl_down(l.x, 1); rr2.y = __shfl_down(l.y, 1);
            rr2.z = __shfl_down(l.z, 1); rr2.w = __shfl_down(l.w, 1);
            if (lane == 0)  ll  = zero4();
            if (lane == 63) rr2 = zero4();
            ohl = hblur9(ll, l, rr2);
        } else {
            ohl = zero4();
        }
    };

#pragma unroll
    for (int i = 0; i < 8; ++i) loadrow(r0 - 4 + i, hlr[i]);

    float nx=0,ny=0,nz=0,nw=0, dx=0,dy=0,dz=0,dw=0;
#pragma unroll
    for (int rr = 0; rr < S_; ++rr) {
        loadrow(r0 + rr + 4, hlr[(rr + 8) % 9]);
        // vertical blur -> bl = blur2d(labels) at output row
        float4 bl = zero4();
#pragma unroll
        for (int j = 0; j < 9; ++j) {
            const float4& aw = hlr[(rr + j) % 9];
            bl.x += G[j]*aw.x; bl.y += G[j]*aw.y; bl.z += G[j]*aw.z; bl.w += G[j]*aw.w;
        }
        int off = (r0 + rr) * W_ + colo;
        float4 l  = ld4(lrow + off);   // L1 hit (loaded 4 iters ago)
        float4 a  = ld4(i0p + off);
        float4 bb = ld4(i1p + off);
        float4 cc = ld4(i2p + off);
        {
            float df = (a.x*a.x + bb.x*bb.x + cc.x*cc.x)
                     - 2.f*(a.x*cm0 + bb.x*cm1 + cc.x*cm2) + m2;
            float t = bl.x * __expf(-(df*df));
            dx += t; nx += t * l.x;
        }
        {
            float df = (a.y*a.y + bb.y*bb.y + cc.y*cc.y)
                     - 2.f*(a.y*cm0 + bb.y*cm1 + cc.y*cm2) + m2;
            float t = bl.y * __expf(-(df*df));
            dy += t; ny += t * l.y;
        }
        {
            float df = (a.z*a.z + bb.z*bb.z + cc.z*cc.z)
                     - 2.f*(a.z*cm0 + bb.z*cm1 + cc.z*cm2) + m2;
            float t = bl.z * __expf(-(df*df));
            dz += t; nz += t * l.z;
        }
        {
            float df = (a.w*a.w + bb.w*bb.w + cc.w*cc.w)
                     - 2.f*(a.w*cm0 + bb.w*cm1 + cc.w*cm2) + m2;
            float t = bl.w * __expf(-(df*df));
            dw += t; nw += t * l.w;
        }
    }
    float num = (nx + ny) + (nz + nw);
    float den = (dx + dy) + (dz + dw);
#pragma unroll
    for (int o = 32; o > 0; o >>= 1) { num += __shfl_xor(num, o); den += __shfl_xor(den, o); }
    if (lane == 0) {
        atomicAdd(&numden[k], num);
        atomicAdd(&numden[K_ + k], den);
    }
}

__global__ void finalize_k(const float* __restrict__ numden, float* __restrict__ out) {
    if (threadIdx.x == 0 && blockIdx.x == 0) {
        float loss = 0.f;
        for (int kk = 0; kk < K_; ++kk)
            loss += fabsf(numden[kk] / (numden[K_ + kk] + 1e-6f));
        out[0] = (float)K_ - loss;
    }
}

extern "C" void kernel_launch(void* const* d_in, const int* in_sizes, int n_in,
                              void* d_out, int out_size, void* d_ws, size_t ws_size,
                              hipStream_t stream) {
    const float* labels = (const float*)d_in[0];
    const float* inputs = (const float*)d_in[1];
    float* ws     = (float*)d_ws;
    float* sums   = ws;                 // 4 * B * K floats
    float* numden = ws + 4 * BK_;       // 2 * K floats
    const int nz = 4 * BK_ + 2 * K_;

    zero_ws_k<<<(nz + 255) / 256, 256, 0, stream>>>(ws, nz);
    stats_k<<<1280, 256, 0, stream>>>(labels, inputs, sums);                        // (b,k,4 chunks)
    fused_k<<<(NSTRIP_ * B_ * 5), 256, 0, stream>>>(labels, inputs, sums, numden);  // 1280 blocks
    finalize_k<<<1, 64, 0, stream>>>(numden, (float*)d_out);
}

// Round 4
// 248.517 us; speedup vs baseline: 1.8919x; 1.8919x over previous
//
#include <hip/hip_runtime.h>

#define B_ 16
#define K_ 20
#define H_ 256
#define W_ 256
#define HW_ (H_*W_)
#define BK_ (B_*K_)
#define TH_ 32       // rows per strip in fused
#define NSTRIP_ 8    // H_/TH_

__device__ __forceinline__ float4 ld4(const float* p) { return *(const float4*)p; }

// exp(-(j-4)^2/50), j=0..8 (separable: exp(-(di^2+dj^2)/50) = g(di)*g(dj))
#define G0_ 0.72614903707f
#define G1_ 0.83527021141f
#define G2_ 0.92311634639f
#define G3_ 0.98019867331f

// Per-(b,k): sum(labels), sum(labels*inputs_c). One block = one (b,k,64-row chunk).
// XCD swizzle: blocks sharing (b,chunk) share blockIdx%8 -> same XCD L2 for inputs.
__global__ __launch_bounds__(256) void stats_k(const float* __restrict__ labels,
                                               const float* __restrict__ inputs,
                                               float* __restrict__ sums) {
    int idx = blockIdx.x;
    int low = idx & 7; int t1 = idx >> 3;
    int k = t1 % K_; int bch = t1 / K_;      // bch in 0..7
    int bc = bch * 8 + low;                  // bc = chunk + 4*b, in 0..63
    int chunk = bc & 3, b = bc >> 2;

    int tid = threadIdx.x;
    int rowi = tid >> 6;                     // 4 rows in flight
    int colo = (tid & 63) * 4;

    const float* lrow = labels + ((size_t)(b * K_ + k)) * HW_;
    const float* ip   = inputs + (size_t)b * 3 * HW_;

    float sl = 0.f, s0 = 0.f, s1 = 0.f, s2 = 0.f;
    int r0 = chunk * 64 + rowi;
#pragma unroll 4
    for (int it = 0; it < 16; ++it) {
        int off = (r0 + it * 4) * W_ + colo;
        float4 l  = ld4(lrow + off);
        float4 a  = ld4(ip + off);
        float4 bb = ld4(ip + HW_ + off);
        float4 cc = ld4(ip + 2 * HW_ + off);
        sl += (l.x + l.y) + (l.z + l.w);
        s0 += l.x * a.x  + l.y * a.y  + l.z * a.z  + l.w * a.w;
        s1 += l.x * bb.x + l.y * bb.y + l.z * bb.z + l.w * bb.w;
        s2 += l.x * cc.x + l.y * cc.y + l.z * cc.z + l.w * cc.w;
    }
#pragma unroll
    for (int o = 32; o > 0; o >>= 1) {
        sl += __shfl_xor(sl, o); s0 += __shfl_xor(s0, o);
        s1 += __shfl_xor(s1, o); s2 += __shfl_xor(s2, o);
    }
    __shared__ float rb[4][4];
    int wv = tid >> 6, lane = tid & 63;
    if (lane == 0) { rb[0][wv] = sl; rb[1][wv] = s0; rb[2][wv] = s1; rb[3][wv] = s2; }
    __syncthreads();
    if (tid == 0) {
        int bk = b * K_ + k;
        atomicAdd(&sums[bk],          rb[0][0] + rb[0][1] + rb[0][2] + rb[0][3]);
        atomicAdd(&sums[BK_ + bk],    rb[1][0] + rb[1][1] + rb[1][2] + rb[1][3]);
        atomicAdd(&sums[2*BK_ + bk],  rb[2][0] + rb[2][1] + rb[2][2] + rb[2][3]);
        atomicAdd(&sums[3*BK_ + bk],  rb[3][0] + rb[3][1] + rb[3][2] + rb[3][3]);
    }
}

// Adjoint: num = sum blur2d(l)*l*w, den = sum blur2d(l)*w  (G symmetric, zero-padded).
// Thread-per-column (round-0 skeleton, VGPR~32, no spill): scalar raw-label ring of 9
// + explicit shift; vertical blur in regs; horizontal via double-buffered LDS row.
// Last block also computes the final loss (device-scope counter).
__global__ __launch_bounds__(256) void fused_k(const float* __restrict__ labels,
                                               const float* __restrict__ inputs,
                                               const float* __restrict__ sums,
                                               float* __restrict__ numden,
                                               unsigned* __restrict__ counter,
                                               float* __restrict__ out) {
    const float G[9] = {G0_, G1_, G2_, G3_, 1.0f, G3_, G2_, G1_, G0_};
    int idx = blockIdx.x;
    int low = idx & 7; int t1 = idx >> 3;
    int k = t1 % K_; int sbh = t1 / K_;      // sbh in 0..15
    int sb = sbh * 8 + low;                  // sb = strip + 8*b, in 0..127
    int strip = sb & (NSTRIP_ - 1), b = sb >> 3;
    int bk = b * K_ + k;
    int x = threadIdx.x;                     // column

    float dn  = sums[bk] + 1e-5f * (float)HW_;
    float inv = 1.f / dn;
    float cm0 = sums[BK_ + bk] * inv;
    float cm1 = sums[2 * BK_ + bk] * inv;
    float cm2 = sums[3 * BK_ + bk] * inv;
    float m2  = cm0 * cm0 + cm1 * cm1 + cm2 * cm2;

    __shared__ float sv[2][W_ + 8];
    if (x < 4) {
        sv[0][x] = 0.f; sv[1][x] = 0.f;
        sv[0][W_ + 4 + x] = 0.f; sv[1][W_ + 4 + x] = 0.f;
    }

    const float* lrow = labels + (size_t)bk * HW_;
    const float* i0p = inputs + (size_t)b * 3 * HW_;
    const float* i1p = i0p + HW_;
    const float* i2p = i0p + 2 * HW_;
    const int r0 = strip * TH_;

    float lab[9];
#pragma unroll
    for (int i = 0; i < 8; ++i) {
        int t = r0 - 4 + i;
        lab[i] = ((unsigned)t < (unsigned)H_) ? lrow[t * W_ + x] : 0.f;
    }
    __syncthreads();   // pads visible

    float num = 0.f, den = 0.f;
    for (int rr = 0; rr < TH_; ++rr) {
        int t = r0 + rr + 4;
        lab[8] = ((unsigned)t < (unsigned)H_) ? lrow[t * W_ + x] : 0.f;
        // vertical 9-tap on raw labels
        float vb = G[0] * lab[0];
#pragma unroll
        for (int i = 1; i < 9; ++i) vb += G[i] * lab[i];
        int bf = rr & 1;
        sv[bf][4 + x] = vb;
        __syncthreads();
        // horizontal 9-tap
        float bl = G[0] * sv[bf][x];
#pragma unroll
        for (int j = 1; j < 9; ++j) bl += G[j] * sv[bf][x + j];
        // point-wise weight and accumulation
        int off = (r0 + rr) * W_ + x;
        float a  = i0p[off], bb = i1p[off], cc = i2p[off];
        float df = (a * a + bb * bb + cc * cc)
                 - 2.f * (a * cm0 + bb * cm1 + cc * cm2) + m2;
        float tt = bl * __expf(-(df * df));
        den += tt; num += tt * lab[4];
        // ring shift (static indices -> pure v_mov, no scratch)
#pragma unroll
        for (int i = 0; i < 8; ++i) lab[i] = lab[i + 1];
    }

#pragma unroll
    for (int o = 32; o > 0; o >>= 1) { num += __shfl_xor(num, o); den += __shfl_xor(den, o); }
    __shared__ float rb[2][4];
    int wv = x >> 6, lane = x & 63;
    if (lane == 0) { rb[0][wv] = num; rb[1][wv] = den; }
    __syncthreads();
    if (x == 0) {
        atomicAdd(&numden[k],      rb[0][0] + rb[0][1] + rb[0][2] + rb[0][3]);
        atomicAdd(&numden[K_ + k], rb[1][0] + rb[1][1] + rb[1][2] + rb[1][3]);
        __threadfence();
        unsigned done = atomicAdd(counter, 1u);
        if (done == gridDim.x - 1u) {   // last block: finalize
            __threadfence();
            float loss = 0.f;
            for (int kk = 0; kk < K_; ++kk) {
                float nu = atomicAdd(&numden[kk], 0.f);       // coherent read
                float de = atomicAdd(&numden[K_ + kk], 0.f);
                loss += fabsf(nu / (de + 1e-6f));
            }
            out[0] = (float)K_ - loss;
        }
    }
}

extern "C" void kernel_launch(void* const* d_in, const int* in_sizes, int n_in,
                              void* d_out, int out_size, void* d_ws, size_t ws_size,
                              hipStream_t stream) {
    const float* labels = (const float*)d_in[0];
    const float* inputs = (const float*)d_in[1];
    float* ws       = (float*)d_ws;
    float* sums     = ws;                        // 4*B*K floats
    float* numden   = ws + 4 * BK_;              // 2*K floats
    unsigned* counter = (unsigned*)(ws + 4 * BK_ + 2 * K_);

    hipMemsetAsync(ws, 0, (4 * BK_ + 2 * K_ + 1) * sizeof(float), stream);
    stats_k<<<1280, 256, 0, stream>>>(labels, inputs, sums);
    fused_k<<<NSTRIP_ * B_ * K_, 256, 0, stream>>>(labels, inputs, sums, numden,
                                                   counter, (float*)d_out);
}